// Round 2
// baseline (747.813 us; speedup 1.0000x reference)
//
#include <hip/hip_runtime.h>
#include <hip/hip_bf16.h>

typedef _Float16 half8 __attribute__((ext_vector_type(8)));
typedef _Float16 half2t __attribute__((ext_vector_type(2)));
typedef float f32x4 __attribute__((ext_vector_type(4)));

#define B_SZ 64
#define T_SZ 512
#define E_SZ 768
#define H_SZ 256
#define V_SZ 3072

// workspace layout (bytes)
#define WS_X     0u          // _Float16 x[T][B][H]           16,777,216 B
#define WS_EMB   16777216u   // _Float16 embf[3072][768]       4,718,592 B
#define WS_WT    21495808u   // _Float16 Wt[256][768] (Wxh^T)    393,216 B
#define WS_WP    21889024u   // uint     Wp[128][256]            131,072 B
#define WS_H     22020096u   // float    h[64][256]               65,536 B

static __device__ __forceinline__ float dot2p(int hp, unsigned int wp, float c) {
#if defined(__has_builtin) && __has_builtin(__builtin_amdgcn_fdot2)
  return __builtin_amdgcn_fdot2(__builtin_bit_cast(half2t, hp),
                                __builtin_bit_cast(half2t, wp), c, false);
#else
  half2t a = __builtin_bit_cast(half2t, hp);
  half2t b = __builtin_bit_cast(half2t, wp);
  return c + (float)a[0]*(float)b[0] + (float)a[1]*(float)b[1];
#endif
}

// ---------------- k0: convert f32 inputs to f16 layouts ----------------
__global__ __launch_bounds__(256) void k0_convert(
    const float* __restrict__ emb,
    const float* __restrict__ Wxh,
    const float* __restrict__ Whh,
    _Float16* __restrict__ embf,
    _Float16* __restrict__ Wt,
    unsigned int* __restrict__ Wp)
{
  int gid = blockIdx.x * 256 + threadIdx.x;          // grid covers 3072*768 exactly
  embf[gid] = (_Float16)emb[gid];
  if (gid < E_SZ * H_SZ) {                            // Wxh[e][h] -> Wt[h][e]
    int e = gid >> 8, h = gid & 255;
    Wt[h * E_SZ + e] = (_Float16)Wxh[gid];
  }
  if (gid < 128 * H_SZ) {                             // pack Whh column pairs as f16x2
    int k = gid >> 8, j = gid & 255;
    _Float16 lo = (_Float16)Whh[(2 * k) * H_SZ + j];
    _Float16 hi = (_Float16)Whh[(2 * k + 1) * H_SZ + j];
    unsigned short lu = __builtin_bit_cast(unsigned short, lo);
    unsigned short hu = __builtin_bit_cast(unsigned short, hi);
    Wp[gid] = (unsigned int)lu | ((unsigned int)hu << 16);
  }
}

// ---------------- k1: x[t,b,:] = emb[idx[b,t],:] @ Wxh  (MFMA f16) ----------------
// WG = 64 rows x 256 cols; wave w handles rows w*16..w*16+15, all 256 cols.
__global__ __launch_bounds__(256) void k1_xproj(
    const int* __restrict__ idx,
    const _Float16* __restrict__ embf,
    const _Float16* __restrict__ Wt,
    _Float16* __restrict__ x)
{
  const int tid  = threadIdx.x;
  const int w    = tid >> 6;
  const int lane = tid & 63;
  const int m16  = lane & 15;
  const int quad = lane >> 4;
  const int r = blockIdx.x * 64 + w * 16 + m16;     // row in [T*B], r = t*64 + b
  const int t = r >> 6;
  const int b = r & 63;
  const int erow = idx[b * T_SZ + t];
  const _Float16* Abase = embf + (size_t)erow * E_SZ + quad * 8;  // A[m=lane&15][k=quad*8+j]
  const _Float16* Bbase = Wt + (size_t)m16 * E_SZ + quad * 8;     // B^T[n=lane&15][k=quad*8+j]
  f32x4 acc[16];
#pragma unroll
  for (int n = 0; n < 16; ++n) { f32x4 z = {0.f, 0.f, 0.f, 0.f}; acc[n] = z; }
#pragma unroll 1
  for (int ki = 0; ki < 24; ++ki) {
    half8 a = *(const half8*)(Abase + ki * 32);
#pragma unroll
    for (int nt = 0; nt < 16; ++nt) {
      half8 bb = *(const half8*)(Bbase + ki * 32 + (size_t)nt * 16 * E_SZ);
      acc[nt] = __builtin_amdgcn_mfma_f32_16x16x32_f16(a, bb, acc[nt], 0, 0, 0);
    }
  }
  const int rbase = blockIdx.x * 64 + w * 16 + quad * 4;  // C/D: col=lane&15, row=quad*4+reg
#pragma unroll
  for (int nt = 0; nt < 16; ++nt) {
    const int col = nt * 16 + m16;
#pragma unroll
    for (int rg = 0; rg < 4; ++rg) {
      x[(size_t)(rbase + rg) * H_SZ + col] = (_Float16)acc[nt][rg];
    }
  }
}

// ---------------- k2: the recurrence, one WG per batch ----------------
__global__ __launch_bounds__(256, 1) void k2_rnn(
    const unsigned int* __restrict__ Wp,
    const _Float16* __restrict__ x,
    const float* __restrict__ Bh,
    float* __restrict__ hout,
    float* __restrict__ hidout)
{
  const int b = blockIdx.x;
  const int j = threadIdx.x;          // output column this thread owns
  const int lane = j & 63;
  __shared__ unsigned int lh[2][128]; // packed f16 pairs of h, double-buffered
  unsigned int wv[128];               // Whh column j, packed pairs, in registers
#pragma unroll
  for (int k = 0; k < 128; ++k) wv[k] = Wp[k * H_SZ + j];
  const float bhj = Bh[j];
  unsigned int hp0 = 0u, hp1 = 0u;    // pairs lane and lane+64 of h (replicated per wave)
  const _Float16* xp = x + b * H_SZ + j;
  _Float16 xq = xp[0];
  float hval = 0.f;
#pragma unroll 1
  for (int t = 0; t < T_SZ; ++t) {
    const int tn = (t < T_SZ - 1) ? (t + 1) : t;
    _Float16 xn = xp[(size_t)tn * (B_SZ * H_SZ)];   // prefetch next step's x
    float a0 = bhj + (float)xq;
    float a1 = 0.f, a2 = 0.f, a3 = 0.f;
#pragma unroll
    for (int k = 0; k < 64; k += 4) {
      a0 = dot2p(__builtin_amdgcn_readlane((int)hp0, k + 0), wv[k + 0], a0);
      a1 = dot2p(__builtin_amdgcn_readlane((int)hp0, k + 1), wv[k + 1], a1);
      a2 = dot2p(__builtin_amdgcn_readlane((int)hp0, k + 2), wv[k + 2], a2);
      a3 = dot2p(__builtin_amdgcn_readlane((int)hp0, k + 3), wv[k + 3], a3);
    }
#pragma unroll
    for (int k = 0; k < 64; k += 4) {
      a0 = dot2p(__builtin_amdgcn_readlane((int)hp1, k + 0), wv[64 + k + 0], a0);
      a1 = dot2p(__builtin_amdgcn_readlane((int)hp1, k + 1), wv[64 + k + 1], a1);
      a2 = dot2p(__builtin_amdgcn_readlane((int)hp1, k + 2), wv[64 + k + 2], a2);
      a3 = dot2p(__builtin_amdgcn_readlane((int)hp1, k + 3), wv[64 + k + 3], a3);
    }
    hval = tanhf((a0 + a1) + (a2 + a3));
    const int p = t & 1;
    _Float16 hh = (_Float16)hval;
    ((unsigned short*)lh[p])[j] = __builtin_bit_cast(unsigned short, hh);
    __syncthreads();
    hp0 = lh[p][lane];
    hp1 = lh[p][64 + lane];
    xq = xn;
  }
  hout[b * H_SZ + j] = hval;
  hidout[b * H_SZ + j] = hval;
}

// ---------------- k3: out = hidden @ Wy + By  (all f32) ----------------
__global__ __launch_bounds__(256) void k3_out(
    const float* __restrict__ h,
    const float* __restrict__ Wy,
    const float* __restrict__ By,
    float* __restrict__ out)
{
  __shared__ float hs[H_SZ];
  const int c = blockIdx.x;   // vocab chunk
  const int b = blockIdx.y;   // batch
  const int v = c * 256 + threadIdx.x;
  hs[threadIdx.x] = h[b * H_SZ + threadIdx.x];
  __syncthreads();
  float acc = By[v];
#pragma unroll 8
  for (int jj = 0; jj < H_SZ; ++jj) {
    acc += hs[jj] * Wy[(size_t)jj * V_SZ + v];
  }
  out[(size_t)b * V_SZ + v] = acc;
}

extern "C" void kernel_launch(void* const* d_in, const int* in_sizes, int n_in,
                              void* d_out, int out_size, void* d_ws, size_t ws_size,
                              hipStream_t stream)
{
  const int*   idx = (const int*)d_in[0];
  const float* emb = (const float*)d_in[1];
  const float* Wxh = (const float*)d_in[2];
  const float* Whh = (const float*)d_in[3];
  const float* Wy  = (const float*)d_in[4];
  const float* By  = (const float*)d_in[5];
  const float* Bh  = (const float*)d_in[6];

  char* ws = (char*)d_ws;
  _Float16*     x    = (_Float16*)(ws + WS_X);
  _Float16*     embf = (_Float16*)(ws + WS_EMB);
  _Float16*     Wt   = (_Float16*)(ws + WS_WT);
  unsigned int* Wp   = (unsigned int*)(ws + WS_WP);
  float*        hbuf = (float*)(ws + WS_H);

  float* out    = (float*)d_out;
  float* hidout = out + (size_t)B_SZ * V_SZ;

  k0_convert<<<9216, 256, 0, stream>>>(emb, Wxh, Whh, embf, Wt, Wp);
  k1_xproj  <<<512, 256, 0, stream>>>(idx, embf, Wt, x);
  k2_rnn    <<<64, 256, 0, stream>>>(Wp, x, Bh, hbuf, hidout);
  k3_out    <<<dim3(12, 64), 256, 0, stream>>>(hbuf, Wy, By, out);
}

// Round 3
// 483.712 us; speedup vs baseline: 1.5460x; 1.5460x over previous
//
#include <hip/hip_runtime.h>
#include <hip/hip_bf16.h>

typedef _Float16 half8 __attribute__((ext_vector_type(8)));
typedef _Float16 half2t __attribute__((ext_vector_type(2)));
typedef float f32x4 __attribute__((ext_vector_type(4)));

#define B_SZ 64
#define T_SZ 512
#define E_SZ 768
#define H_SZ 256
#define V_SZ 3072

// workspace layout (bytes)
#define WS_X     0u          // _Float16 x[T][B][H]           16,777,216 B
#define WS_EMB   16777216u   // _Float16 embf[3072][768]       4,718,592 B
#define WS_WT    21495808u   // _Float16 Wt[256][768] (Wxh^T)    393,216 B
#define WS_WP    21889024u   // uint     Wp[256][128] ([j][k])   131,072 B
#define WS_H     22020096u   // float    h[64][256]               65,536 B

static __device__ __forceinline__ float dot2p(int hp, unsigned int wp, float c) {
#if defined(__has_builtin) && __has_builtin(__builtin_amdgcn_fdot2)
  return __builtin_amdgcn_fdot2(__builtin_bit_cast(half2t, hp),
                                __builtin_bit_cast(half2t, wp), c, false);
#else
  half2t a = __builtin_bit_cast(half2t, hp);
  half2t b = __builtin_bit_cast(half2t, wp);
  return c + (float)a[0]*(float)b[0] + (float)a[1]*(float)b[1];
#endif
}

// fast tanh: 1 - 2/(1+exp(2x)); exact at +/-inf, ~1e-6 rel err
static __device__ __forceinline__ float fast_tanh(float x) {
  float e = __builtin_amdgcn_exp2f(x * 2.8853900817779268f); // exp(2x)
  return 1.0f - 2.0f * __builtin_amdgcn_rcpf(1.0f + e);
}

// ---------------- k0: convert f32 inputs to f16 layouts ----------------
__global__ __launch_bounds__(256) void k0_convert(
    const float* __restrict__ emb,
    const float* __restrict__ Wxh,
    const float* __restrict__ Whh,
    _Float16* __restrict__ embf,
    _Float16* __restrict__ Wt,
    unsigned int* __restrict__ Wp)
{
  int gid = blockIdx.x * 256 + threadIdx.x;          // grid covers 3072*768 exactly
  embf[gid] = (_Float16)emb[gid];
  if (gid < E_SZ * H_SZ) {                            // Wxh[e][h] -> Wt[h][e]
    int e = gid >> 8, h = gid & 255;
    Wt[h * E_SZ + e] = (_Float16)Wxh[gid];
  }
  if (gid < 128 * H_SZ) {                             // pack Whh pairs, layout [j][k]
    int k = gid >> 8, j = gid & 255;                  // pair k = rows 2k,2k+1, col j
    _Float16 lo = (_Float16)Whh[(2 * k) * H_SZ + j];
    _Float16 hi = (_Float16)Whh[(2 * k + 1) * H_SZ + j];
    unsigned short lu = __builtin_bit_cast(unsigned short, lo);
    unsigned short hu = __builtin_bit_cast(unsigned short, hi);
    Wp[j * 128 + k] = (unsigned int)lu | ((unsigned int)hu << 16);
  }
}

// ---------------- k1: x[t,b,:] = emb[idx[b,t],:] @ Wxh  (MFMA f16) ----------------
__global__ __launch_bounds__(256) void k1_xproj(
    const int* __restrict__ idx,
    const _Float16* __restrict__ embf,
    const _Float16* __restrict__ Wt,
    _Float16* __restrict__ x)
{
  const int tid  = threadIdx.x;
  const int w    = tid >> 6;
  const int lane = tid & 63;
  const int m16  = lane & 15;
  const int quad = lane >> 4;
  const int r = blockIdx.x * 64 + w * 16 + m16;     // row in [T*B], r = t*64 + b
  const int t = r >> 6;
  const int b = r & 63;
  const int erow = idx[b * T_SZ + t];
  const _Float16* Abase = embf + (size_t)erow * E_SZ + quad * 8;
  const _Float16* Bbase = Wt + (size_t)m16 * E_SZ + quad * 8;
  f32x4 acc[16];
#pragma unroll
  for (int n = 0; n < 16; ++n) { f32x4 z = {0.f, 0.f, 0.f, 0.f}; acc[n] = z; }
#pragma unroll 1
  for (int ki = 0; ki < 24; ++ki) {
    half8 a = *(const half8*)(Abase + ki * 32);
#pragma unroll
    for (int nt = 0; nt < 16; ++nt) {
      half8 bb = *(const half8*)(Bbase + ki * 32 + (size_t)nt * 16 * E_SZ);
      acc[nt] = __builtin_amdgcn_mfma_f32_16x16x32_f16(a, bb, acc[nt], 0, 0, 0);
    }
  }
  const int rbase = blockIdx.x * 64 + w * 16 + quad * 4;  // C/D: col=lane&15, row=quad*4+reg
#pragma unroll
  for (int nt = 0; nt < 16; ++nt) {
    const int col = nt * 16 + m16;
#pragma unroll
    for (int rg = 0; rg < 4; ++rg) {
      x[(size_t)(rbase + rg) * H_SZ + col] = (_Float16)acc[nt][rg];
    }
  }
}

// ---------------- k2: the recurrence, one WG per batch ----------------
// Thread j owns output column j. Whh column j lives in 32 named uint4 VGPRs
// (no array -> no alloca -> no scratch spill; VGPR budget 512 @ 1 wave/EU).
// h broadcast: all lanes ds_read_b128 the same address (broadcast, no conflict).
#define DECLW(c) uint4 w##c = Wp4[(size_t)j * 32 + c];
#define STEP4(c) { uint4 hc = lv[c]; \
  a0 = dot2p((int)hc.x, w##c.x, a0); \
  a1 = dot2p((int)hc.y, w##c.y, a1); \
  a2 = dot2p((int)hc.z, w##c.z, a2); \
  a3 = dot2p((int)hc.w, w##c.w, a3); }
#define REP32(M) M(0) M(1) M(2) M(3) M(4) M(5) M(6) M(7) \
  M(8) M(9) M(10) M(11) M(12) M(13) M(14) M(15) \
  M(16) M(17) M(18) M(19) M(20) M(21) M(22) M(23) \
  M(24) M(25) M(26) M(27) M(28) M(29) M(30) M(31)

__global__ __launch_bounds__(256, 1) void k2_rnn(
    const unsigned int* __restrict__ Wp,
    const _Float16* __restrict__ x,
    const float* __restrict__ Bh,
    float* __restrict__ hout,
    float* __restrict__ hidout)
{
  const int b = blockIdx.x;
  const int j = threadIdx.x;                 // output column this thread owns
  __shared__ __align__(16) unsigned int lh[2][128]; // packed f16 pairs of h, dbuf
  const uint4* Wp4 = (const uint4*)Wp;
  REP32(DECLW)                               // 128 VGPRs of Whh column j
  const float bhj = Bh[j];
  const _Float16* xp = x + b * H_SZ + j;
  _Float16 xq = xp[0];
  float hval = 0.f;
  if (j < 128) lh[1][j] = 0u;                // iter 0 reads buf1 = zeros
  __syncthreads();
#pragma unroll 1
  for (int t = 0; t < T_SZ; ++t) {
    const int tn = (t < T_SZ - 1) ? (t + 1) : t;
    _Float16 xn = xp[(size_t)tn * (B_SZ * H_SZ)];   // prefetch next step's x
    const uint4* lv = (const uint4*)lh[(t + 1) & 1]; // read buffer (broadcast)
    float a0 = bhj + (float)xq;
    float a1 = 0.f, a2 = 0.f, a3 = 0.f;
    REP32(STEP4)                             // 32 broadcast b128 reads + 128 dot2
    hval = fast_tanh((a0 + a1) + (a2 + a3));
    _Float16 hh = (_Float16)hval;
    ((unsigned short*)lh[t & 1])[j] = __builtin_bit_cast(unsigned short, hh);
    __syncthreads();
    xq = xn;
  }
  hout[b * H_SZ + j] = hval;
  hidout[b * H_SZ + j] = hval;
}

// ---------------- k3: out = hidden @ Wy + By  (all f32) ----------------
__global__ __launch_bounds__(256) void k3_out(
    const float* __restrict__ h,
    const float* __restrict__ Wy,
    const float* __restrict__ By,
    float* __restrict__ out)
{
  __shared__ float hs[H_SZ];
  const int c = blockIdx.x;   // vocab chunk
  const int b = blockIdx.y;   // batch
  const int v = c * 256 + threadIdx.x;
  hs[threadIdx.x] = h[b * H_SZ + threadIdx.x];
  __syncthreads();
  float acc = By[v];
#pragma unroll 8
  for (int jj = 0; jj < H_SZ; ++jj) {
    acc += hs[jj] * Wy[(size_t)jj * V_SZ + v];
  }
  out[(size_t)b * V_SZ + v] = acc;
}

extern "C" void kernel_launch(void* const* d_in, const int* in_sizes, int n_in,
                              void* d_out, int out_size, void* d_ws, size_t ws_size,
                              hipStream_t stream)
{
  const int*   idx = (const int*)d_in[0];
  const float* emb = (const float*)d_in[1];
  const float* Wxh = (const float*)d_in[2];
  const float* Whh = (const float*)d_in[3];
  const float* Wy  = (const float*)d_in[4];
  const float* By  = (const float*)d_in[5];
  const float* Bh  = (const float*)d_in[6];

  char* ws = (char*)d_ws;
  _Float16*     x    = (_Float16*)(ws + WS_X);
  _Float16*     embf = (_Float16*)(ws + WS_EMB);
  _Float16*     Wt   = (_Float16*)(ws + WS_WT);
  unsigned int* Wp   = (unsigned int*)(ws + WS_WP);
  float*        hbuf = (float*)(ws + WS_H);

  float* out    = (float*)d_out;
  float* hidout = out + (size_t)B_SZ * V_SZ;

  k0_convert<<<9216, 256, 0, stream>>>(emb, Wxh, Whh, embf, Wt, Wp);
  k1_xproj  <<<512, 256, 0, stream>>>(idx, embf, Wt, x);
  k2_rnn    <<<64, 256, 0, stream>>>(Wp, x, Bh, hbuf, hidout);
  k3_out    <<<dim3(12, 64), 256, 0, stream>>>(hbuf, Wy, By, out);
}